// Round 1
// baseline (751.524 us; speedup 1.0000x reference)
//
#include <hip/hip_runtime.h>

// Soft-DTW forward: B=64 batches, N=M=512, gamma=0.1, penalty=0, bandwidth>=N+M (no-op).
// One block per batch; thread t owns DP row i=t+1. Anti-diagonal wavefront with
// double-buffered LDS line for the neighbor-row exchange; 1 barrier per diagonal.

constexpr int Bn = 64;
constexpr int Nn = 512;
constexpr int Mn = 512;
constexpr float GAMMA = 0.1f;

__device__ __forceinline__ float exp2_fast(float x) {
    float r; asm("v_exp_f32 %0, %1" : "=v"(r) : "v"(x)); return r;
}
__device__ __forceinline__ float log2_fast(float x) {
    float r; asm("v_log_f32 %0, %1" : "=v"(r) : "v"(x)); return r;
}

__global__ __launch_bounds__(Nn) void softdtw_fwd(
    const float* __restrict__ D, const float* __restrict__ Msk,
    const int* __restrict__ xlens, const int* __restrict__ ylens,
    float* __restrict__ out)
{
    const int b  = blockIdx.x;
    const int ii = threadIdx.x + 1;           // DP row index, 1..512
    const int xl = xlens[b];
    const int yl = ylens[b];
    const int s_target = xl + yl;             // diagonal holding the output cell

    __shared__ float buf[2][Nn + 1];          // slot 0 = permanent inf border
    if (threadIdx.x == 0) { buf[0][0] = INFINITY; buf[1][0] = INFINITY; }

    const float* __restrict__ Drow = D   + ((size_t)b * Nn + (ii - 1)) * Mn;
    const float* __restrict__ Mrow = Msk + ((size_t)b * Nn + (ii - 1)) * Mn;

    const float kexp = 1.4426950408889634f / GAMMA;   // log2(e)/gamma
    const float klog = 0.6931471805599453f * GAMMA;   // gamma*ln(2)

    // Register state:
    //   dm1_own : d[s-1][ii]    (own row, previous diagonal)
    //   dm1_nb  : d[s-1][ii-1]  (neighbor row, previous diagonal)
    //   dm2_nb  : d[s-2][ii-1]  (neighbor row, diagonal before that)
    float dm1_own = INFINITY;
    float dm1_nb  = INFINITY;
    float dm2_nb  = (ii == 1) ? 0.0f : INFINITY;   // d[s=0][0] = 0, rest inf

    __syncthreads();

    for (int s = 2; s <= s_target; ++s) {
        const int jj = s - ii;
        float newv = INFINITY;
        if ((jj >= 1) & (jj <= Mn) & (ii <= xl) & (jj <= yl)) {
            const float c0 = dm2_nb;   // d[i-1][j-1]
            const float c1 = dm1_nb;   // d[i-1][j]
            const float c2 = dm1_own;  // d[i][j-1]
            const float m = fminf(fminf(c0, c1), c2);
            float sm = INFINITY;
            if (m < INFINITY) {
                // softmin = m - gamma*ln2 * log2( 2^{(m-c0)k} + 2^{(m-c1)k} + 2^{(m-c2)k} )
                // (m - c_i) <= 0; c_i == inf gives exp2(-inf) = 0, matching the reference.
                const float e0 = exp2_fast((m - c0) * kexp);
                const float e1 = exp2_fast((m - c1) * kexp);
                const float e2 = exp2_fast((m - c2) * kexp);
                sm = m - klog * log2_fast(e0 + e1 + e2);
            }
            newv = Drow[jj - 1] * Mrow[jj - 1] + sm;
        }
        // rotate register state for next diagonal
        dm1_own = newv;
        dm2_nb  = dm1_nb;
        buf[s & 1][ii] = newv;
        __syncthreads();
        dm1_nb = buf[s & 1][ii - 1];
    }

    // After the s == s_target iteration, dm1_own holds d[ii][s_target - ii];
    // the output cell is (xl, yl).
    if (ii == xl) out[b] = dm1_own;
}

extern "C" void kernel_launch(void* const* d_in, const int* in_sizes, int n_in,
                              void* d_out, int out_size, void* d_ws, size_t ws_size,
                              hipStream_t stream) {
    const float* D   = (const float*)d_in[0];
    const float* Msk = (const float*)d_in[1];
    const int*   xl  = (const int*)d_in[2];
    const int*   yl  = (const int*)d_in[3];
    float* out = (float*)d_out;
    softdtw_fwd<<<dim3(Bn), dim3(Nn), 0, stream>>>(D, Msk, xl, yl, out);
}

// Round 2
// 241.585 us; speedup vs baseline: 3.1108x; 3.1108x over previous
//
#include <hip/hip_runtime.h>

// Soft-DTW forward, B=64, N=M=512, gamma=0.1, penalty=0, bandwidth no-op.
// One wave (64 lanes) per batch. Lane t owns DP columns j = 8t+1 .. 8t+8 and
// at step k processes row i = k - t (systolic skew, lag 1 row per lane).
// Vertical deps: registers (dprev). Horizontal deps: serial 8-cell chain in
// registers. Cross-lane boundary: one __shfl_up per step. No barriers, no LDS.
//
// Whole recurrence kept scaled by kexp = log2(e)/gamma. Since gamma*ln2 ==
// 1/kexp, softmin in scaled domain is:  smk = m3k - log2(sum exp2(m3k - cik)).
// Cell update: nvk = (D*mask)*kexp + smk;  unscale only for the final output.

constexpr int Bn = 64, Nn = 512, Mn = 512;
constexpr float GAMMA = 0.1f;

__device__ __forceinline__ float exp2_fast(float x) {
    float r; asm("v_exp_f32 %0, %1" : "=v"(r) : "v"(x)); return r;
}
__device__ __forceinline__ float log2_fast(float x) {
    float r; asm("v_log_f32 %0, %1" : "=v"(r) : "v"(x)); return r;
}

__global__ __launch_bounds__(64) void softdtw_fwd(
    const float* __restrict__ D, const float* __restrict__ Msk,
    const int* __restrict__ xlens, const int* __restrict__ ylens,
    float* __restrict__ out)
{
    const int b = blockIdx.x;
    const int t = threadIdx.x;                 // lane 0..63
    const int xl = xlens[b];
    const int yl = ylens[b];
    const int cb = t * 8;                      // owns DP columns cb+1 .. cb+8
    const int t_out  = (yl - 1) >> 3;
    const int rr_out = (yl - 1) & 7;
    const int kmax   = xl + t_out;             // step at which output cell is computed
    const int ncols  = min(max(yl - cb, 0), 8);

    const float kexp = 1.4426950408889634f / GAMMA;  // log2(e)/gamma
    const float klog = 0.6931471805599453f * GAMMA;  // gamma*ln2 == 1/kexp
    const float INF  = __builtin_inff();

    const float4* __restrict__ D4 = (const float4*)(D   + (size_t)b * (Nn * Mn));
    const float4* __restrict__ M4 = (const float4*)(Msk + (size_t)b * (Nn * Mn));
    const int chunk = t * 2;                   // float4 index of this lane's columns

    // dprevk[rr] = kexp * d[i-1][cb+1+rr]  (row above, own columns)
    float dprevk[8];
    #pragma unroll
    for (int r = 0; r < 8; ++r) dprevk[r] = INF;
    // Ldk = kexp*d[i-1][cb] (diag-left), Lhk = kexp*d[i][cb] (horiz-left)
    float Ldk = (t == 0) ? 0.0f : INF;         // d[0][0] = 0
    float Lhk = INF;

    float4 nDa = {0,0,0,0}, nDb = {0,0,0,0}, nMa = {0,0,0,0}, nMb = {0,0,0,0};
    // prefetch row for k=1 (i = 1 - t): only lane 0 is in-range
    if (1 - t >= 1) {
        int o = (0) * (Mn / 4) + chunk;
        nDa = D4[o]; nDb = D4[o + 1]; nMa = M4[o]; nMb = M4[o + 1];
    }

    float ov = INF;                            // scaled value at (row i, col yl) for lane t_out

    for (int k = 1; k <= kmax; ++k) {
        const int  i    = k - t;
        const bool rowv = (i >= 1) & (i <= xl);

        const float4 cDa = nDa, cDb = nDb, cMa = nMa, cMb = nMb;
        // prefetch next row (i+1)
        {
            const int i2 = i + 1;
            if ((i2 >= 1) & (i2 <= xl)) {
                int o = (i2 - 1) * (Mn / 4) + chunk;
                nDa = D4[o]; nDb = D4[o + 1]; nMa = M4[o]; nMb = M4[o + 1];
            }
        }

        float ek[8];
        ek[0] = cDa.x * cMa.x * kexp;  ek[1] = cDa.y * cMa.y * kexp;
        ek[2] = cDa.z * cMa.z * kexp;  ek[3] = cDa.w * cMa.w * kexp;
        ek[4] = cDb.x * cMb.x * kexp;  ek[5] = cDb.y * cMb.y * kexp;
        ek[6] = cDb.z * cMb.z * kexp;  ek[7] = cDb.w * cMb.w * kexp;

        float c0 = Ldk;                        // scaled d[i-1][j-1]
        float c2 = Lhk;                        // scaled d[i][j-1]
        #pragma unroll
        for (int rr = 0; rr < 8; ++rr) {
            const float c1  = dprevk[rr];      // scaled d[i-1][j]
            const float m3  = fminf(fminf(c0, c1), c2);
            const float s   = exp2_fast(m3 - c0) + exp2_fast(m3 - c1) + exp2_fast(m3 - c2);
            float nvk = ek[rr] + (m3 - log2_fast(s));
            const bool ok = rowv & (m3 < INF) & (rr < ncols);
            nvk = ok ? nvk : INF;
            c0 = c1;                           // diag for next col = old row-above value
            c2 = nvk;                          // horiz for next col
            dprevk[rr] = nvk;
            if (rr == rr_out) ov = nvk;        // candidate output (valid at k == kmax)
        }

        // pass this lane's rightmost new value (scaled d[i][cb+8]) to lane t+1
        const float recvk = __shfl_up(c2, 1);
        Ldk = Lhk;                             // d[i][cb] becomes next step's diagonal
        Lhk = recvk;                           // d[i+1][cb] from left neighbor
        if (t == 0) { Ldk = INF; Lhk = INF; }  // column 0 border is inf for all i >= 1
    }

    if (t == t_out) out[b] = ov * klog;        // unscale
}

extern "C" void kernel_launch(void* const* d_in, const int* in_sizes, int n_in,
                              void* d_out, int out_size, void* d_ws, size_t ws_size,
                              hipStream_t stream) {
    const float* D   = (const float*)d_in[0];
    const float* Msk = (const float*)d_in[1];
    const int*   xl  = (const int*)d_in[2];
    const int*   yl  = (const int*)d_in[3];
    float* out = (float*)d_out;
    softdtw_fwd<<<dim3(Bn), dim3(64), 0, stream>>>(D, Msk, xl, yl, out);
}

// Round 4
// 157.300 us; speedup vs baseline: 4.7776x; 1.5358x over previous
//
#include <hip/hip_runtime.h>

// Soft-DTW forward, B=64, N=M=512, gamma=0.1, penalty=0, bandwidth no-op.
// One wave per batch; lane t owns columns 8t+1..8t+8, systolic row skew.
// Linear-domain (sum-product): E = exp(-d/gamma),
//   E[i][j] = W[i][j] * (E[i-1][j-1] + E[i-1][j] + E[i][j-1]),
//   W = exp2(-D*mask*log2e/gamma).  Serial per-cell dep = 1 FMA.
// Per-lane scale S (true = stored * 2^S). Each step renormalizes to
// TARGET_E = -60 anchored at max(own chain end, incoming boundary) --
// this bounds every stored value <= 2^56 and sums <= 2^60: overflow to
// inf is impossible by construction (round-3 failure mode eliminated).
// Output captured PRE-rescale and logged via frexp decomposition so
// log2 only ever sees a normal mantissa.

constexpr int Bn = 64, Nn = 512, Mn = 512;
constexpr int TARGET_E = -60;

__device__ __forceinline__ float exp2_fast(float x) {
    float r; asm("v_exp_f32 %0, %1" : "=v"(r) : "v"(x)); return r;
}
__device__ __forceinline__ float log2_fast(float x) {
    float r; asm("v_log_f32 %0, %1" : "=v"(r) : "v"(x)); return r;
}
__device__ __forceinline__ float ldexp_fast(float x, int e) {
    float r; asm("v_ldexp_f32 %0, %1, %2" : "=v"(r) : "v"(x), "v"(e)); return r;
}
__device__ __forceinline__ int frexp_exp(float x) {
    int r; asm("v_frexp_exp_i32_f32 %0, %1" : "=v"(r) : "v"(x)); return r;
}

// One wavefront step: chain for step KK using weights WC; prefetch row KK+2
// into NXT; max-anchored rescale + boundary shfl; build WN (weights for
// step KK+1) from ARR.
#define SOFTDTW_STEP(KK, WC, WN, ARR, NXT)                                     \
    {                                                                          \
        const int k_ = (KK);                                                   \
        {   int i2_ = min(max(k_ + 2 - t, 1), Nn);                             \
            int o_ = (i2_ - 1) * (Mn / 4) + chunk;                             \
            NXT##da = D4[o_]; NXT##db = D4[o_ + 1];                            \
            NXT##ma = M4[o_]; NXT##mb = M4[o_ + 1]; }                          \
        float c0_ = Ld, c2_ = Lh;                                              \
        _Pragma("unroll")                                                      \
        for (int rr = 0; rr < 8; ++rr) {                                       \
            float e1_ = E[rr];                                                 \
            float A_  = e1_ + c0_;                                             \
            float B_  = WC[rr] * A_;                                           \
            float nv_ = fmaf(WC[rr], c2_, B_);                                 \
            c0_ = e1_;  E[rr] = nv_;  c2_ = nv_;                               \
            if (rr == rr_out) ov = nv_;                                        \
        }                                                                      \
        ovS = S;                            /* scale of this step's chain */   \
        float c2o_ = __shfl_up(c2_, 1);                                        \
        int   So_  = __shfl_up(S, 1);                                          \
        int  e_own_ = frexp_exp(c2_);                                          \
        int  e_inc_ = frexp_exp(c2o_) + (So_ - S);                             \
        bool inc_ok_ = (t != 0) && (c2o_ != 0.0f);                             \
        int  e_ref_ = (inc_ok_ && ((e_inc_ > e_own_) || (c2_ == 0.0f)))        \
                          ? e_inc_ : e_own_;                                   \
        int  shift_ = ((c2_ == 0.0f) && !inc_ok_) ? 0 : (TARGET_E - e_ref_);   \
        const bool virgin_ = (k_ <= t);                                        \
        if (virgin_) shift_ = 0;                                               \
        int Snew_ = virgin_ ? So_ : (S - shift_);                              \
        _Pragma("unroll")                                                      \
        for (int rr = 0; rr < 8; ++rr) E[rr] = ldexp_fast(E[rr], shift_);      \
        float Ldn_ = ldexp_fast(Lh, shift_);                                   \
        float Lhn_ = ldexp_fast(c2o_, So_ - Snew_);                            \
        if (t == 0) { Ldn_ = 0.0f; Lhn_ = 0.0f; }                              \
        Ld = Ldn_; Lh = Lhn_; S = Snew_;                                       \
        WN[0] = exp2_fast(ARR##da.x * ARR##ma.x * negk);                       \
        WN[1] = exp2_fast(ARR##da.y * ARR##ma.y * negk);                       \
        WN[2] = exp2_fast(ARR##da.z * ARR##ma.z * negk);                       \
        WN[3] = exp2_fast(ARR##da.w * ARR##ma.w * negk);                       \
        WN[4] = exp2_fast(ARR##db.x * ARR##mb.x * negk);                       \
        WN[5] = exp2_fast(ARR##db.y * ARR##mb.y * negk);                       \
        WN[6] = exp2_fast(ARR##db.z * ARR##mb.z * negk);                       \
        WN[7] = exp2_fast(ARR##db.w * ARR##mb.w * negk);                       \
    }

__global__ __launch_bounds__(64) void softdtw_fwd(
    const float* __restrict__ D, const float* __restrict__ Msk,
    const int* __restrict__ xlens, const int* __restrict__ ylens,
    float* __restrict__ out)
{
    const int b = blockIdx.x;
    const int t = threadIdx.x;
    const int xl = xlens[b];
    const int yl = ylens[b];
    const int t_out  = (yl - 1) >> 3;
    const int rr_out = (yl - 1) & 7;
    const int kmax   = xl + t_out;

    const float negk = -14.4269504088896341f;   // -log2(e)/gamma
    const float klog = 0.06931471805599453f;    // gamma*ln2

    const float4* __restrict__ D4 = (const float4*)(D   + (size_t)b * (Nn * Mn));
    const float4* __restrict__ M4 = (const float4*)(Msk + (size_t)b * (Nn * Mn));
    const int chunk = t * 2;

    float E[8];
#pragma unroll
    for (int r = 0; r < 8; ++r) E[r] = 0.0f;
    float Ld = (t == 0) ? 1.0f : 0.0f;          // E(d[0][0]) = 1; rest borders 0
    float Lh = 0.0f;
    int S = 0;
    float ov = 0.0f;                            // pre-rescale output candidate
    int ovS = 0;

    float W0[8], W1[8];
    float4 bAda, bAdb, bAma, bAmb;
    float4 bBda, bBdb, bBma, bBmb;

    {   // prologue: W for step 1; data for step 2
        int i1 = min(max(1 - t, 1), Nn);
        int o  = (i1 - 1) * (Mn / 4) + chunk;
        float4 da = D4[o], db = D4[o + 1], ma = M4[o], mb = M4[o + 1];
        W0[0] = exp2_fast(da.x * ma.x * negk);
        W0[1] = exp2_fast(da.y * ma.y * negk);
        W0[2] = exp2_fast(da.z * ma.z * negk);
        W0[3] = exp2_fast(da.w * ma.w * negk);
        W0[4] = exp2_fast(db.x * mb.x * negk);
        W0[5] = exp2_fast(db.y * mb.y * negk);
        W0[6] = exp2_fast(db.z * mb.z * negk);
        W0[7] = exp2_fast(db.w * mb.w * negk);
        int i2 = min(max(2 - t, 1), Nn);
        o = (i2 - 1) * (Mn / 4) + chunk;
        bAda = D4[o]; bAdb = D4[o + 1]; bAma = M4[o]; bAmb = M4[o + 1];
    }

    int k = 1;
    for (; k + 1 <= kmax; k += 2) {
        SOFTDTW_STEP(k,     W0, W1, bA, bB);
        SOFTDTW_STEP(k + 1, W1, W0, bB, bA);
    }
    if (k <= kmax) SOFTDTW_STEP(k, W0, W1, bA, bB);

    if (t == t_out) {
        // ov is the (xl, yl) chain value at scale ovS, captured pre-rescale.
        int   ev = frexp_exp(ov);
        float mv = ldexp_fast(ov, -ev);         // normal mantissa in [0.5, 1)
        out[b] = -(log2_fast(mv) + (float)(ev + ovS)) * klog;
    }
}

extern "C" void kernel_launch(void* const* d_in, const int* in_sizes, int n_in,
                              void* d_out, int out_size, void* d_ws, size_t ws_size,
                              hipStream_t stream) {
    const float* D   = (const float*)d_in[0];
    const float* Msk = (const float*)d_in[1];
    const int*   xl  = (const int*)d_in[2];
    const int*   yl  = (const int*)d_in[3];
    float* out = (float*)d_out;
    softdtw_fwd<<<dim3(Bn), dim3(64), 0, stream>>>(D, Msk, xl, yl, out);
}

// Round 5
// 145.942 us; speedup vs baseline: 5.1495x; 1.0778x over previous
//
#include <hip/hip_runtime.h>

// Soft-DTW forward, B=64, N=M=512, gamma=0.1, penalty=0, bandwidth no-op.
// One wave per batch; lane t owns columns 8t+1..8t+8. 4-row macro-steps:
// lane t processes rows 4(m-t)+1..4(m-t)+4 at macro-step m. Linear-domain
// sum-product: E = exp(-d/gamma), E[i][j] = W*(E[nw]+E[n]+E[w]),
// W = exp2(-D*mask*log2e/gamma). Boundary (4 chain-end values + scale)
// crosses lanes via shfl_up once per macro-step; per-lane pow2 scale S
// re-anchored to TARGET_E at max(own chain end, incoming) once per
// macro-step. Virgin/out-of-range tiles compute garbage that is provably
// contained (flows only into other garbage); lanes zero E/Ld at their
// first real tile (m==t). Per-cell FMA sequence identical to round 4.

constexpr int Bn = 64, Nn = 512, Mn = 512;
constexpr int TARGET_E = -30;

__device__ __forceinline__ float exp2_fast(float x) {
    float r; asm("v_exp_f32 %0, %1" : "=v"(r) : "v"(x)); return r;
}
__device__ __forceinline__ float log2_fast(float x) {
    float r; asm("v_log_f32 %0, %1" : "=v"(r) : "v"(x)); return r;
}
__device__ __forceinline__ float ldexp_fast(float x, int e) {
    float r; asm("v_ldexp_f32 %0, %1, %2" : "=v"(r) : "v"(x), "v"(e)); return r;
}
__device__ __forceinline__ int frexp_exp(float x) {
    int r; asm("v_frexp_exp_i32_f32 %0, %1" : "=v"(r) : "v"(x)); return r;
}

// Load the 4 rows (D and mask, 2 float4 each) for macro-step MM into buffer.
#define LOADROWS(MM, BD, BM)                                                   \
    {   const int base_ = 4 * ((MM) - t);                                      \
        _Pragma("unroll")                                                      \
        for (int rr = 0; rr < 4; ++rr) {                                       \
            int r_ = min(max(base_ + rr, 0), Nn - 1);                          \
            int o_ = r_ * (Mn / 4) + chunk;                                    \
            BD[rr][0] = D4[o_];  BD[rr][1] = D4[o_ + 1];                       \
            BM[rr][0] = M4[o_];  BM[rr][1] = M4[o_ + 1];                       \
        } }

#define BUILDW(BD, BM)                                                         \
    {   _Pragma("unroll")                                                      \
        for (int rr = 0; rr < 4; ++rr) {                                       \
            float4 p_ = BD[rr][0] * BM[rr][0] * negk;                          \
            float4 q_ = BD[rr][1] * BM[rr][1] * negk;                          \
            W[rr][0] = exp2_fast(p_.x); W[rr][1] = exp2_fast(p_.y);            \
            W[rr][2] = exp2_fast(p_.z); W[rr][3] = exp2_fast(p_.w);            \
            W[rr][4] = exp2_fast(q_.x); W[rr][5] = exp2_fast(q_.y);            \
            W[rr][6] = exp2_fast(q_.z); W[rr][7] = exp2_fast(q_.w);            \
        } }

// One macro-step MM: issue loads for MM+2 into BI_*, compute 4x8 tile with
// current W, transfer boundary + rescale, build W for MM+1 from BW_*.
#define STEP(MM, BI_D, BI_M, BW_D, BW_M)                                       \
    {                                                                          \
        LOADROWS((MM) + 2, BI_D, BI_M);                                        \
        if ((MM) == t && t != 0) {                                             \
            _Pragma("unroll")                                                  \
            for (int c = 0; c < 8; ++c) E[c] = 0.0f;                           \
            Ld = 0.0f;                                                         \
        }                                                                      \
        float ce[4], co[4];                                                    \
        _Pragma("unroll")                                                      \
        for (int rr = 0; rr < 4; ++rr) {                                       \
            float c0_ = (rr == 0) ? Ld : L[rr - 1];                            \
            float c2_ = L[rr];                                                 \
            float A_[8], Bv_[8];                                               \
            A_[0] = E[0] + c0_;                                                \
            _Pragma("unroll")                                                  \
            for (int c = 1; c < 8; ++c) A_[c] = E[c] + E[c - 1];               \
            _Pragma("unroll")                                                  \
            for (int c = 0; c < 8; ++c) Bv_[c] = W[rr][c] * A_[c];             \
            _Pragma("unroll")                                                  \
            for (int c = 0; c < 8; ++c) {                                      \
                float nv_ = fmaf(W[rr][c], c2_, Bv_[c]);                       \
                E[c] = nv_;  c2_ = nv_;                                        \
            }                                                                  \
            ce[rr] = c2_;  co[rr] = __shfl_up(c2_, 1);                         \
            if ((MM) == m_out && rr == r_out) {   /* block-uniform */          \
                float sel_ = E[0];                                             \
                if (c_out == 1) sel_ = E[1];  if (c_out == 2) sel_ = E[2];     \
                if (c_out == 3) sel_ = E[3];  if (c_out == 4) sel_ = E[4];     \
                if (c_out == 5) sel_ = E[5];  if (c_out == 6) sel_ = E[6];     \
                if (c_out == 7) sel_ = E[7];                                   \
                ov = sel_;  ovS = S;                                           \
            }                                                                  \
        }                                                                      \
        int So_ = __shfl_up(S, 1);                                             \
        int eo_ = frexp_exp(ce[3]);                                            \
        int ei_ = frexp_exp(co[3]) + (So_ - S);                                \
        bool own0_  = (ce[3] == 0.0f);                                         \
        bool incok_ = (t != 0) && (co[3] != 0.0f);                             \
        int  eref_  = (incok_ && ((ei_ > eo_) || own0_)) ? ei_ : eo_;          \
        int  shift_ = (own0_ && !incok_) ? 0 : (TARGET_E - eref_);             \
        if ((MM) < t) shift_ = S - So_;        /* virgin: adopt sender */      \
        int Snew_ = S - shift_;                                                \
        _Pragma("unroll")                                                      \
        for (int c = 0; c < 8; ++c) E[c] = ldexp_fast(E[c], shift_);           \
        Ld = ldexp_fast(L[3], shift_);                                         \
        {   int d_ = So_ - Snew_;                                              \
            _Pragma("unroll")                                                  \
            for (int rr = 0; rr < 4; ++rr)                                     \
                L[rr] = (t == 0) ? 0.0f : ldexp_fast(co[rr], d_);              \
        }                                                                      \
        S = Snew_;                                                             \
        BUILDW(BW_D, BW_M);                                                    \
    }

__global__ __launch_bounds__(64) void softdtw_fwd(
    const float* __restrict__ D, const float* __restrict__ Msk,
    const int* __restrict__ xlens, const int* __restrict__ ylens,
    float* __restrict__ out)
{
    const int b = blockIdx.x;
    const int t = threadIdx.x;
    const int xl = xlens[b];
    const int yl = ylens[b];
    const int t_out = (yl - 1) >> 3;            // lane holding output col
    const int c_out = (yl - 1) & 7;             // col slot within lane
    const int r_out = (xl - 1) & 3;             // row slot within tile
    const int m_out = ((xl - 1) >> 2) + t_out;  // macro-step of output cell

    const float negk = -14.4269504088896341f;   // -log2(e)/gamma
    const float klog = 0.06931471805599453f;    // gamma*ln2

    const float4* __restrict__ D4 = (const float4*)(D   + (size_t)b * (Nn * Mn));
    const float4* __restrict__ M4 = (const float4*)(Msk + (size_t)b * (Nn * Mn));
    const int chunk = t * 2;

    float E[8];
#pragma unroll
    for (int c = 0; c < 8; ++c) E[c] = 0.0f;
    float L[4] = {0.0f, 0.0f, 0.0f, 0.0f};      // left boundary, 4 rows
    float Ld = (t == 0) ? 1.0f : 0.0f;          // diag boundary: E(d[0][0]) = 1
    int S = 0;
    float ov = 1.0f;  int ovS = 0;

    float W[4][8];
    float4 bAD[4][2], bAM[4][2];                // two in-flight row buffers
    float4 bBD[4][2], bBM[4][2];

    // prologue: W for m=0; buffer rows for m=1
    LOADROWS(0, bAD, bAM);
    BUILDW(bAD, bAM);
    LOADROWS(1, bBD, bBM);

    int m = 0;
    for (; m + 1 <= m_out; m += 2) {
        STEP(m,     bAD, bAM, bBD, bBM);
        STEP(m + 1, bBD, bBM, bAD, bAM);
    }
    if (m <= m_out) STEP(m, bAD, bAM, bBD, bBM);

    if (t == t_out) {
        int   ev = frexp_exp(ov);
        float mv = ldexp_fast(ov, -ev);         // normal mantissa in [0.5,1)
        out[b] = -(log2_fast(mv) + (float)(ev + ovS)) * klog;
    }
}

extern "C" void kernel_launch(void* const* d_in, const int* in_sizes, int n_in,
                              void* d_out, int out_size, void* d_ws, size_t ws_size,
                              hipStream_t stream) {
    const float* D   = (const float*)d_in[0];
    const float* Msk = (const float*)d_in[1];
    const int*   xl  = (const int*)d_in[2];
    const int*   yl  = (const int*)d_in[3];
    float* out = (float*)d_out;
    softdtw_fwd<<<dim3(Bn), dim3(64), 0, stream>>>(D, Msk, xl, yl, out);
}

// Round 6
// 145.657 us; speedup vs baseline: 5.1595x; 1.0020x over previous
//
#include <hip/hip_runtime.h>

// Soft-DTW forward, B=64, N=M=512, gamma=0.1, penalty=0, bandwidth no-op.
// Producer/consumer: 3 waves per block (192 thr). Wave 0 = DP consumer
// (systolic chain, rescale, output). Waves 1,2 = W producers: load D/mask
// rows, build W = exp2(-D*mask*log2e/gamma), write 4x8 W-tiles per lane to
// a 6-slot LDS ring. Consumer reads W via ds_read_b128, double-buffered one
// macro-step ahead. One __syncthreads per super-step (2 macro-steps).
// Ring safety (mod 6): super-step u reads slots {2u,2u+1,2u+2}, writes
// {2u+4,2u+5} -- disjoint offsets {0,1,2} vs {4,5}. Slot m written at
// super-step (m-4)/2, read at u=m/2: >= 2 barriers apart. Numerics are
// identical to round 5 (linear-domain sum-product, per-lane pow2 scale S
// re-anchored to TARGET_E at max(own chain end, incoming boundary)).

constexpr int Bn = 64, Nn = 512, Mn = 512;
constexpr int TARGET_E = -30;

__device__ __forceinline__ float exp2_fast(float x) {
    float r; asm("v_exp_f32 %0, %1" : "=v"(r) : "v"(x)); return r;
}
__device__ __forceinline__ float log2_fast(float x) {
    float r; asm("v_log_f32 %0, %1" : "=v"(r) : "v"(x)); return r;
}
__device__ __forceinline__ float ldexp_fast(float x, int e) {
    float r; asm("v_ldexp_f32 %0, %1, %2" : "=v"(r) : "v"(x), "v"(e)); return r;
}
__device__ __forceinline__ int frexp_exp(float x) {
    int r; asm("v_frexp_exp_i32_f32 %0, %1" : "=v"(r) : "v"(x)); return r;
}

// ---- producer: load 4 rows (D,mask) for macro-step MM into pD/pM ----
#define PLOAD(MM)                                                              \
    {   const int base_ = 4 * ((MM) - t);                                      \
        _Pragma("unroll")                                                      \
        for (int rr = 0; rr < 4; ++rr) {                                       \
            int r_ = min(max(base_ + rr, 0), Nn - 1);                          \
            int o_ = r_ * (Mn / 4) + chunk;                                    \
            pD[rr][0] = D4[o_];  pD[rr][1] = D4[o_ + 1];                       \
            pM[rr][0] = M4[o_];  pM[rr][1] = M4[o_ + 1];                       \
        } }

// ---- producer: build W tile for macro-step MM from pD/pM, write ring ----
#define PBUILD(MM)                                                             \
    {   const int s_ = (MM) % 6;                                               \
        _Pragma("unroll")                                                      \
        for (int rr = 0; rr < 4; ++rr) {                                       \
            float4 p_ = pD[rr][0] * pM[rr][0] * negk;                          \
            float4 q_ = pD[rr][1] * pM[rr][1] * negk;                          \
            float4 wa_, wb_;                                                   \
            wa_.x = exp2_fast(p_.x);  wa_.y = exp2_fast(p_.y);                 \
            wa_.z = exp2_fast(p_.z);  wa_.w = exp2_fast(p_.w);                 \
            wb_.x = exp2_fast(q_.x);  wb_.y = exp2_fast(q_.y);                 \
            wb_.z = exp2_fast(q_.z);  wb_.w = exp2_fast(q_.w);                 \
            wlds[s_][2 * rr][t]     = wa_;                                     \
            wlds[s_][2 * rr + 1][t] = wb_;                                     \
        } }

// ---- consumer: one macro-step MM using WCUR; prefetch slot MM+1 -> WNXT ----
#define CSTEP(MM, WCUR, WNXT)                                                  \
    {                                                                          \
        const int m_ = (MM);                                                   \
        {   const int sn_ = (m_ + 1) % 6;                                      \
            _Pragma("unroll")                                                  \
            for (int rr = 0; rr < 4; ++rr) {                                   \
                WNXT[rr][0] = wlds[sn_][2 * rr][t];                            \
                WNXT[rr][1] = wlds[sn_][2 * rr + 1][t];                        \
            } }                                                                \
        if (m_ <= 63) {                  /* uniform wrapper */                 \
            if (m_ == t && t != 0) {                                           \
                _Pragma("unroll")                                              \
                for (int c = 0; c < 8; ++c) E[c] = 0.0f;                       \
                Ld = 0.0f;                                                     \
            }                                                                  \
        }                                                                      \
        float ce3_, co_[4];                                                    \
        _Pragma("unroll")                                                      \
        for (int rr = 0; rr < 4; ++rr) {                                       \
            const float Wr_[8] = {                                             \
                WCUR[rr][0].x, WCUR[rr][0].y, WCUR[rr][0].z, WCUR[rr][0].w,    \
                WCUR[rr][1].x, WCUR[rr][1].y, WCUR[rr][1].z, WCUR[rr][1].w };  \
            const float c0s_ = (rr == 0) ? Ld : L[rr - 1];                     \
            float c2_ = L[rr];                                                 \
            float A_[8], Bv_[8];                                               \
            A_[0] = E[0] + c0s_;                                               \
            _Pragma("unroll")                                                  \
            for (int c = 1; c < 8; ++c) A_[c] = E[c] + E[c - 1];               \
            _Pragma("unroll")                                                  \
            for (int c = 0; c < 8; ++c) Bv_[c] = Wr_[c] * A_[c];               \
            _Pragma("unroll")                                                  \
            for (int c = 0; c < 8; ++c) {                                      \
                float nv_ = fmaf(Wr_[c], c2_, Bv_[c]);                         \
                E[c] = nv_;  c2_ = nv_;                                        \
            }                                                                  \
            if (rr == 3) ce3_ = c2_;                                           \
            co_[rr] = __shfl_up(c2_, 1);                                       \
            if (m_ == m_out && rr == r_out) {   /* uniform: taken once */      \
                float sel_ = E[0];                                             \
                if (c_out == 1) sel_ = E[1];  if (c_out == 2) sel_ = E[2];     \
                if (c_out == 3) sel_ = E[3];  if (c_out == 4) sel_ = E[4];     \
                if (c_out == 5) sel_ = E[5];  if (c_out == 6) sel_ = E[6];     \
                if (c_out == 7) sel_ = E[7];                                   \
                ov = sel_;  ovS = S;                                           \
            }                                                                  \
        }                                                                      \
        int So_ = __shfl_up(S, 1);                                             \
        int eo_ = frexp_exp(ce3_);                                             \
        int ei_ = frexp_exp(co_[3]) + (So_ - S);                               \
        bool own0_  = (ce3_ == 0.0f);                                          \
        bool incok_ = (t != 0) && (co_[3] != 0.0f);                            \
        int  eref_  = (incok_ && ((ei_ > eo_) || own0_)) ? ei_ : eo_;          \
        int  shift_ = (own0_ && !incok_) ? 0 : (TARGET_E - eref_);             \
        if (m_ < t) shift_ = S - So_;          /* virgin: adopt sender */      \
        int Snew_ = S - shift_;                                                \
        _Pragma("unroll")                                                      \
        for (int c = 0; c < 8; ++c) E[c] = ldexp_fast(E[c], shift_);           \
        Ld = ldexp_fast(L[3], shift_);                                         \
        {   int d_ = So_ - Snew_;                                              \
            _Pragma("unroll")                                                  \
            for (int rr = 0; rr < 4; ++rr)                                     \
                L[rr] = (t == 0) ? 0.0f : ldexp_fast(co_[rr], d_);             \
        }                                                                      \
        S = Snew_;                                                             \
    }

__global__ __launch_bounds__(192) void softdtw_fwd(
    const float* __restrict__ D, const float* __restrict__ Msk,
    const int* __restrict__ xlens, const int* __restrict__ ylens,
    float* __restrict__ out)
{
    const int tid = threadIdx.x;
    const int w   = tid >> 6;                   // 0 = consumer, 1/2 = producers
    const int t   = tid & 63;
    const int b   = blockIdx.x;
    const int xl = xlens[b];
    const int yl = ylens[b];
    const int t_out = (yl - 1) >> 3;
    const int c_out = (yl - 1) & 7;
    const int r_out = (xl - 1) & 3;
    const int m_out = ((xl - 1) >> 2) + t_out;
    const int nsuper = (m_out >> 1) + 1;

    const float negk = -14.4269504088896341f;   // -log2(e)/gamma
    const float klog = 0.06931471805599453f;    // gamma*ln2

    __shared__ float4 wlds[6][8][64];           // [slot][2*rr+half][lane], 48 KiB

    const float4* __restrict__ D4 = (const float4*)(D   + (size_t)b * (Nn * Mn));
    const float4* __restrict__ M4 = (const float4*)(Msk + (size_t)b * (Nn * Mn));
    const int chunk = t * 2;

    // consumer state
    float E[8];
#pragma unroll
    for (int c = 0; c < 8; ++c) E[c] = 0.0f;
    float L[4] = {0.0f, 0.0f, 0.0f, 0.0f};
    float Ld = (t == 0) ? 1.0f : 0.0f;
    int S = 0;
    float ov = 1.0f;  int ovS = 0;
    float4 Wc[4][2], Wn[4][2];

    // producer state
    float4 pD[4][2], pM[4][2];

    // ---- prologue: producers fill slots 0..3 and prime their load buffer ----
    if (w == 1) {
        PLOAD(0); PBUILD(0);
        PLOAD(2); PBUILD(2);
        PLOAD(4);
    } else if (w == 2) {
        PLOAD(1); PBUILD(1);
        PLOAD(3); PBUILD(3);
        PLOAD(5);
    }
    __syncthreads();
    if (w == 0) {
#pragma unroll
        for (int rr = 0; rr < 4; ++rr) {
            Wc[rr][0] = wlds[0][2 * rr][t];
            Wc[rr][1] = wlds[0][2 * rr + 1][t];
        }
    }

    // ---- main loop: one barrier per super-step (2 macro-steps) ----
    for (int u = 0; u < nsuper; ++u) {
        if (w == 0) {
            CSTEP(2 * u, Wc, Wn);
            if (2 * u + 1 <= m_out) CSTEP(2 * u + 1, Wn, Wc);
        } else if (w == 1) {
            PBUILD(2 * u + 4);
            PLOAD(2 * u + 6);
        } else {
            PBUILD(2 * u + 5);
            PLOAD(2 * u + 7);
        }
        __syncthreads();
    }

    if (w == 0 && t == t_out) {
        int   ev = frexp_exp(ov);
        float mv = ldexp_fast(ov, -ev);         // normal mantissa in [0.5,1)
        out[b] = -(log2_fast(mv) + (float)(ev + ovS)) * klog;
    }
}

extern "C" void kernel_launch(void* const* d_in, const int* in_sizes, int n_in,
                              void* d_out, int out_size, void* d_ws, size_t ws_size,
                              hipStream_t stream) {
    const float* D   = (const float*)d_in[0];
    const float* Msk = (const float*)d_in[1];
    const int*   xl  = (const int*)d_in[2];
    const int*   yl  = (const int*)d_in[3];
    float* out = (float*)d_out;
    softdtw_fwd<<<dim3(Bn), dim3(192), 0, stream>>>(D, Msk, xl, yl, out);
}